// Round 16
// baseline (414.241 us; speedup 1.0000x reference)
//
#include <hip/hip_runtime.h>
#include <hip/hip_bf16.h>

#define B_ 4
#define S_ 2048
#define H_ 8
#define E_ 64
#define NW 4      // waves per attention block
#define QB 16     // q rows per wave
#define KT 64     // k/v tile size
#define NT (S_ / KT)
#define HSPLIT 4  // proj: head-groups per s-tile (2 heads per block)

typedef __attribute__((ext_vector_type(8))) short bf16x8v;
typedef __attribute__((ext_vector_type(4))) float f32x4v;

static __device__ __forceinline__ unsigned short f2bf(float f) {
    __hip_bfloat16 h = __float2bfloat16(f);
    return *reinterpret_cast<unsigned short*>(&h);
}

// async global->LDS DMA, 16B/lane
static __device__ __forceinline__ void gl_lds16(const void* g, void* lds) {
    __builtin_amdgcn_global_load_lds(
        (const __attribute__((address_space(1))) unsigned int*)g,
        (__attribute__((address_space(3))) unsigned int*)lds, 16, 0, 0);
}

// ---------------------------------------------------------------------------
// Projection (R9, ~5us, HBM-bound): q scaled into exp2 domain, K plain,
// V pre-transposed. grid = B * S/16 * HSPLIT, block = 192.
// ---------------------------------------------------------------------------
__global__ __launch_bounds__(192)
void proj_kernel(const float* __restrict__ query, const float* __restrict__ key,
                 const float* __restrict__ value,
                 const float* __restrict__ Wq, const float* __restrict__ bq,
                 const float* __restrict__ Wk, const float* __restrict__ bk,
                 const float* __restrict__ Wv, const float* __restrict__ bv,
                 __hip_bfloat16* __restrict__ qp, __hip_bfloat16* __restrict__ kp,
                 __hip_bfloat16* __restrict__ vtp)
{
    const int tid  = threadIdx.x;
    const int wave = tid >> 6;
    const int lane = tid & 63;
    const int lr   = lane & 15;
    const int lh   = lane >> 4;
    const int ntile = S_ / 16;
    const int hb    = blockIdx.x % HSPLIT;
    const int sbase = ((blockIdx.x / HSPLIT) % ntile) * 16;
    const int b     = blockIdx.x / (ntile * HSPLIT);

    const float* x    = (wave == 0) ? query : (wave == 1) ? key : value;
    const float* W    = (wave == 0) ? Wq    : (wave == 1) ? Wk  : Wv;
    const float* bias = (wave == 0) ? bq    : (wave == 1) ? bk  : bv;

    bf16x8v wf[4][2];
#pragma unroll
    for (int cb = 0; cb < 4; ++cb)
#pragma unroll
        for (int hf = 0; hf < 2; ++hf)
#pragma unroll
            for (int j = 0; j < 8; ++j) {
                int e = lh * 8 + j + 32 * hf;
                wf[cb][hf][j] = (short)f2bf(W[e * E_ + cb * 16 + lr]);
            }

    float4 bias4[4];
    float  bvals[4];
#pragma unroll
    for (int cb = 0; cb < 4; ++cb) {
        bias4[cb] = *reinterpret_cast<const float4*>(bias + cb * 16 + 4 * lh);
        bvals[cb] = bias[cb * 16 + lr];
    }

    const float QSCALE = 0.18033688011112042f;   // log2e / 8

#pragma unroll
    for (int hi = 0; hi < H_ / HSPLIT; ++hi) {
        const int h = hb * (H_ / HSPLIT) + hi;
        const float* xrow = x + (((size_t)b * S_ + sbase + lr) * H_ + h) * E_;
        const float4* xr = reinterpret_cast<const float4*>(xrow);
        float4 a0 = xr[lh * 2], a1 = xr[lh * 2 + 1];
        float4 a2 = xr[8 + lh * 2], a3 = xr[8 + lh * 2 + 1];
        bf16x8v af[2];
        af[0][0] = (short)f2bf(a0.x); af[0][1] = (short)f2bf(a0.y);
        af[0][2] = (short)f2bf(a0.z); af[0][3] = (short)f2bf(a0.w);
        af[0][4] = (short)f2bf(a1.x); af[0][5] = (short)f2bf(a1.y);
        af[0][6] = (short)f2bf(a1.z); af[0][7] = (short)f2bf(a1.w);
        af[1][0] = (short)f2bf(a2.x); af[1][1] = (short)f2bf(a2.y);
        af[1][2] = (short)f2bf(a2.z); af[1][3] = (short)f2bf(a2.w);
        af[1][4] = (short)f2bf(a3.x); af[1][5] = (short)f2bf(a3.y);
        af[1][6] = (short)f2bf(a3.z); af[1][7] = (short)f2bf(a3.w);

        if (wave < 2) {
            __hip_bfloat16* dst = (wave == 0) ? qp : kp;
            const float scl = (wave == 0) ? QSCALE : 1.0f;
#pragma unroll
            for (int cb = 0; cb < 4; ++cb) {
                f32x4v acc = {0.f, 0.f, 0.f, 0.f};
                acc = __builtin_amdgcn_mfma_f32_16x16x32_bf16(wf[cb][0], af[0], acc, 0, 0, 0);
                acc = __builtin_amdgcn_mfma_f32_16x16x32_bf16(wf[cb][1], af[1], acc, 0, 0, 0);
                ushort4 o;
                o.x = f2bf((acc[0] + bias4[cb].x) * scl);
                o.y = f2bf((acc[1] + bias4[cb].y) * scl);
                o.z = f2bf((acc[2] + bias4[cb].z) * scl);
                o.w = f2bf((acc[3] + bias4[cb].w) * scl);
                *reinterpret_cast<ushort4*>(
                    (unsigned short*)dst +
                    (((size_t)b * H_ + h) * S_ + sbase + lr) * E_ + cb * 16 + 4 * lh) = o;
            }
        } else {
#pragma unroll
            for (int cb = 0; cb < 4; ++cb) {
                f32x4v acc = {0.f, 0.f, 0.f, 0.f};
                acc = __builtin_amdgcn_mfma_f32_16x16x32_bf16(af[0], wf[cb][0], acc, 0, 0, 0);
                acc = __builtin_amdgcn_mfma_f32_16x16x32_bf16(af[1], wf[cb][1], acc, 0, 0, 0);
                float bv4 = bvals[cb];
                ushort4 o;
                o.x = f2bf(acc[0] + bv4);
                o.y = f2bf(acc[1] + bv4);
                o.z = f2bf(acc[2] + bv4);
                o.w = f2bf(acc[3] + bv4);
                *reinterpret_cast<ushort4*>(
                    (unsigned short*)vtp +
                    (((size_t)b * H_ + h) * E_ + cb * 16 + lr) * S_ + sbase + 4 * lh) = o;
            }
        }
    }
}

// ---------------------------------------------------------------------------
// Flash attention = R10 (best: gl_lds dbuf + uniform counted vmcnt(4)
// boundary + strided coalesced mask + raw exp2 + deferred denominator)
// with the mask prefetch deepened to TWO tiles ahead. Same-parity tiles
// share one register quad: pack mask(t), then reload the quad with
// mask(t+2) -> zero copies, uniform boundaries, 8 mask loads in flight.
// grid = B*H * S/(QB*NW) = 1024, block = 256
// ---------------------------------------------------------------------------
struct SOff { unsigned kA, kB, vA, vB; int lo; };

template<bool STG, bool MLD>
static __device__ __forceinline__ void tile_phase(
    int kt, const char* kgb, const char* vgb, const char* mwb,
    char* KtC, char* VsC, char* KtN, char* VsN, SOff so,
    int4& q0, int4& q1, int4& q2, int4& q3,   // mask(kt); reloaded w/ mask(kt+2)
    bf16x8v aq0, bf16x8v aq1, char* PtB, int lr, int lh,
    float (&psum)[4], f32x4v (&Oa)[4])
{
    // ---- stage K/V for tile kt+1 FIRST (must stay the 4 oldest vmem)
    if constexpr (STG) {
        const size_t kadd = (size_t)(kt + 1) * (KT * E_ * 2);
        const size_t vadd = (size_t)(kt + 1) * (KT * 2);
        gl_lds16(kgb + kadd + so.kA, KtN + so.lo);
        gl_lds16(kgb + kadd + so.kB, KtN + so.lo + 1024);
        gl_lds16(vgb + vadd + so.vA, VsN + so.lo);
        gl_lds16(vgb + vadd + so.vB, VsN + so.lo + 1024);
    }
    __builtin_amdgcn_sched_barrier(0);

    // ---- pack THIS tile's mask (regs loaded two tiles ago, landed)
    unsigned long long wm;
    {
        unsigned n0 = (q0.x & 1) | ((q0.y & 1) << 1) | ((q0.z & 1) << 2) | ((q0.w & 1) << 3);
        unsigned n1 = (q1.x & 1) | ((q1.y & 1) << 1) | ((q1.z & 1) << 2) | ((q1.w & 1) << 3);
        unsigned n2 = (q2.x & 1) | ((q2.y & 1) << 1) | ((q2.z & 1) << 2) | ((q2.w & 1) << 3);
        unsigned n3 = (q3.x & 1) | ((q3.y & 1) << 1) | ((q3.z & 1) << 2) | ((q3.w & 1) << 3);
        int sh = lh * 4;
        wm = ((unsigned long long)n0 << sh) |
             ((unsigned long long)n1 << (sh + 16)) |
             ((unsigned long long)n2 << (sh + 32)) |
             ((unsigned long long)n3 << (sh + 48));
        wm |= __shfl_xor(wm, 16);
        wm |= __shfl_xor(wm, 32);   // all 4 lanes of row lr hold the word
    }

    // ---- reload the quad with mask(kt+2) (same parity -> same regs)
    if constexpr (MLD) {
        const char* mp = mwb + (size_t)(kt + 2) * (KT * 4);
        q0 = *reinterpret_cast<const int4*>(mp);
        q1 = *reinterpret_cast<const int4*>(mp + 64);
        q2 = *reinterpret_cast<const int4*>(mp + 128);
        q3 = *reinterpret_cast<const int4*>(mp + 192);
    }
    __builtin_amdgcn_sched_barrier(0);

    // ---- QK^T : D layout row = 4*lh+r (q), col = lr (k within cb)
    f32x4v sc[4];
#pragma unroll
    for (int cb = 0; cb < 4; ++cb) {
        int kcol = cb * 16 + lr;
        bf16x8v bk0 = *reinterpret_cast<bf16x8v*>(
            KtC + ((kcol * 128 + lh * 16) ^ ((kcol & 7) << 4)));
        bf16x8v bk1 = *reinterpret_cast<bf16x8v*>(
            KtC + ((kcol * 128 + 64 + lh * 16) ^ ((kcol & 7) << 4)));
        f32x4v a = {0.f, 0.f, 0.f, 0.f};
        a = __builtin_amdgcn_mfma_f32_16x16x32_bf16(aq0, bk0, a, 0, 0, 0);
        a = __builtin_amdgcn_mfma_f32_16x16x32_bf16(aq1, bk1, a, 0, 0, 0);
        sc[cb] = a;
    }

    // ---- P = exp2(sc) raw; per-lane partial denominators; P -> LDS
#pragma unroll
    for (int r = 0; r < 4; ++r) {
        int q = 4 * lh + r;
        float rs = 0.f;
#pragma unroll
        for (int cb = 0; cb < 4; ++cb) {
            float pv = __builtin_amdgcn_exp2f(sc[cb][r]);
            rs += pv;
            *reinterpret_cast<unsigned short*>(
                PtB + ((q * 128 + (cb * 16 + lr) * 2) ^ ((q & 7) << 4))) = f2bf(pv);
        }
        psum[r] += rs;
    }

    // ---- PV, dropout via bit-test on the row word (k = mh*32 + lh*8 + j)
#pragma unroll
    for (int mh = 0; mh < 2; ++mh) {
        int k0 = mh * 32 + lh * 8;
        bf16x8v pa = *reinterpret_cast<bf16x8v*>(
            PtB + ((lr * 128 + k0 * 2) ^ ((lr & 7) << 4)));
        unsigned mby = (unsigned)(wm >> ((mh * 4 + lh) * 8)) & 0xffu;
#pragma unroll
        for (int j = 0; j < 8; ++j)
            pa[j] = (mby & (1u << j)) ? pa[j] : (short)0;
#pragma unroll
        for (int eb = 0; eb < 4; ++eb) {
            int e = eb * 16 + lr;
            bf16x8v vb = *reinterpret_cast<bf16x8v*>(
                VsC + ((e * 128 + k0 * 2) ^ ((e & 7) << 4)));
            Oa[eb] = __builtin_amdgcn_mfma_f32_16x16x32_bf16(pa, vb, Oa[eb], 0, 0, 0);
        }
    }

    // ---- uniform counted boundary: staging landed; young mask loads fly on
    if constexpr (STG) {
        asm volatile("s_waitcnt vmcnt(4)" ::: "memory");
    } else {
        asm volatile("s_waitcnt vmcnt(0)" ::: "memory");
    }
    __builtin_amdgcn_s_barrier();
    __builtin_amdgcn_sched_barrier(0);
}

__global__ __launch_bounds__(256, 4)
void attn_kernel(const __hip_bfloat16* __restrict__ qp,
                 const __hip_bfloat16* __restrict__ kp,
                 const __hip_bfloat16* __restrict__ vtp,
                 const int* __restrict__ mask,
                 float* __restrict__ out)
{
    __shared__ unsigned short Kt[2][KT * E_];    // swizzled [k][e], dbuf
    __shared__ unsigned short Vs[2][KT * E_];    // swizzled [e][k], dbuf
    __shared__ unsigned short Pt[NW][16 * KT];   // swizzled [q][k], per wave

    const int tid  = threadIdx.x;
    const int wave = tid >> 6;
    const int lane = tid & 63;
    const int lr   = lane & 15;
    const int lh   = lane >> 4;
    const int nqt  = S_ / (QB * NW);
    const int bh   = blockIdx.x / nqt;
    const int qt   = blockIdx.x % nqt;
    const int qbase = qt * (QB * NW) + wave * QB;

    const __hip_bfloat16* qrow = qp + ((size_t)bh * S_ + qbase + lr) * E_;
    bf16x8v aq0 = *reinterpret_cast<const bf16x8v*>(qrow + lh * 8);
    bf16x8v aq1 = *reinterpret_cast<const bf16x8v*>(qrow + lh * 8 + 32);

    float psum[4];
    f32x4v Oa[4];
#pragma unroll
    for (int r = 0; r < 4; ++r) psum[r] = 0.f;
#pragma unroll
    for (int eb = 0; eb < 4; ++eb) Oa[eb] = {0.f, 0.f, 0.f, 0.f};

    const char* kgb = (const char*)(kp  + (size_t)bh * S_ * E_);
    const char* vgb = (const char*)(vtp + (size_t)bh * E_ * S_);
    // coalesced mask base: lane covers row lr, 16B chunk lh (of 4 per 64B seg)
    const char* mwb = (const char*)mask +
        (((size_t)bh * S_ + qbase + lr) * S_) * 4 + lh * 16;

    const int rowA = wave * 16 + (lane >> 3);
    const int rowB = rowA + 8;
    const int e2   = (((lane & 7) ^ (lane >> 3)) << 4);
    SOff so;
    so.kA = (unsigned)rowA * 128 + e2;
    so.kB = (unsigned)rowB * 128 + e2;
    so.vA = (unsigned)rowA * (S_ * 2) + e2;
    so.vB = (unsigned)rowB * (S_ * 2) + e2;
    so.lo = wave * 2048;

    char* Kt0 = (char*)(Kt[0]); char* Kt1 = (char*)(Kt[1]);
    char* Vs0 = (char*)(Vs[0]); char* Vs1 = (char*)(Vs[1]);
    char* PtB = (char*)(Pt[wave]);

    // two mask quads: A = even tiles, B = odd tiles
    int4 mA0, mA1, mA2, mA3, mB0, mB1, mB2, mB3;

    // ---- prologue: stage tile 0 (oldest 4 vmem); mask(0)->A, mask(1)->B
    gl_lds16(kgb + so.kA, Kt0 + so.lo);
    gl_lds16(kgb + so.kB, Kt0 + so.lo + 1024);
    gl_lds16(vgb + so.vA, Vs0 + so.lo);
    gl_lds16(vgb + so.vB, Vs0 + so.lo + 1024);
    __builtin_amdgcn_sched_barrier(0);
    mA0 = *reinterpret_cast<const int4*>(mwb);
    mA1 = *reinterpret_cast<const int4*>(mwb + 64);
    mA2 = *reinterpret_cast<const int4*>(mwb + 128);
    mA3 = *reinterpret_cast<const int4*>(mwb + 192);
    {
        const char* mp = mwb + (size_t)KT * 4;
        mB0 = *reinterpret_cast<const int4*>(mp);
        mB1 = *reinterpret_cast<const int4*>(mp + 64);
        mB2 = *reinterpret_cast<const int4*>(mp + 128);
        mB3 = *reinterpret_cast<const int4*>(mp + 192);
    }
    __builtin_amdgcn_sched_barrier(0);
    asm volatile("s_waitcnt vmcnt(8)" ::: "memory");
    __builtin_amdgcn_s_barrier();
    __builtin_amdgcn_sched_barrier(0);

    // tiles 0..29: full pipeline (stage t+1, mask t+2)
    for (int j = 0; j < 15; ++j) {
        tile_phase<true, true>(2 * j,     kgb, vgb, mwb, Kt0, Vs0, Kt1, Vs1, so,
                               mA0, mA1, mA2, mA3, aq0, aq1, PtB, lr, lh, psum, Oa);
        tile_phase<true, true>(2 * j + 1, kgb, vgb, mwb, Kt1, Vs1, Kt0, Vs0, so,
                               mB0, mB1, mB2, mB3, aq0, aq1, PtB, lr, lh, psum, Oa);
    }
    // tile 30: stage 31, no mask reload; tile 31: neither
    tile_phase<true, false>(30, kgb, vgb, mwb, Kt0, Vs0, Kt1, Vs1, so,
                            mA0, mA1, mA2, mA3, aq0, aq1, PtB, lr, lh, psum, Oa);
    tile_phase<false, false>(31, kgb, vgb, mwb, Kt1, Vs1, Kt0, Vs0, so,
                             mB0, mB1, mB2, mB3, aq0, aq1, PtB, lr, lh, psum, Oa);

    // ---- epilogue: reduce denominators once; out = O * (1/0.9) / lsum
    constexpr float KEEP_INV = 1.0f / 0.9f;
    float* orow = out + ((size_t)bh * S_ + qbase) * E_;
#pragma unroll
    for (int r = 0; r < 4; ++r) {
        float s = psum[r];
#pragma unroll
        for (int off = 1; off < 16; off <<= 1)
            s += __shfl_xor(s, off);
        float inv = KEEP_INV / s;
        int q = 4 * lh + r;
#pragma unroll
        for (int eb = 0; eb < 4; ++eb)
            orow[(size_t)q * E_ + eb * 16 + lr] = Oa[eb][r] * inv;
    }
}

extern "C" void kernel_launch(void* const* d_in, const int* in_sizes, int n_in,
                              void* d_out, int out_size, void* d_ws, size_t ws_size,
                              hipStream_t stream) {
    (void)in_sizes; (void)n_in; (void)out_size; (void)ws_size;
    const float* query = (const float*)d_in[0];
    const float* key   = (const float*)d_in[1];
    const float* value = (const float*)d_in[2];
    const float* Wq    = (const float*)d_in[3];
    const float* bq    = (const float*)d_in[4];
    const float* Wk    = (const float*)d_in[5];
    const float* bk    = (const float*)d_in[6];
    const float* Wv    = (const float*)d_in[7];
    const float* bv    = (const float*)d_in[8];
    const int*   mask  = (const int*)d_in[9];
    float*       out   = (float*)d_out;

    const size_t per = (size_t)B_ * H_ * S_ * E_;
    __hip_bfloat16* qp  = (__hip_bfloat16*)d_ws;
    __hip_bfloat16* kp  = qp + per;
    __hip_bfloat16* vtp = kp + per;

    proj_kernel<<<B_ * (S_ / 16) * HSPLIT, 192, 0, stream>>>(query, key, value,
                                                             Wq, bq, Wk, bk, Wv, bv,
                                                             qp, kp, vtp);
    attn_kernel<<<B_ * H_ * (S_ / (QB * NW)), 256, 0, stream>>>(qp, kp, vtp, mask, out);
}

// Round 18
// 171.377 us; speedup vs baseline: 2.4171x; 2.4171x over previous
//
#include <hip/hip_runtime.h>
#include <hip/hip_bf16.h>

#define B_ 4
#define S_ 2048
#define H_ 8
#define E_ 64
#define NW 4      // waves per attention block
#define QB 16     // q rows per wave
#define KT 64     // k/v tile size
#define NT (S_ / KT)
#define HSPLIT 4  // proj: head-groups per s-tile (2 heads per block)

typedef __attribute__((ext_vector_type(8))) short bf16x8v;
typedef __attribute__((ext_vector_type(4))) float f32x4v;

static __device__ __forceinline__ unsigned short f2bf(float f) {
    __hip_bfloat16 h = __float2bfloat16(f);
    return *reinterpret_cast<unsigned short*>(&h);
}

// async global->LDS DMA, 16B/lane
static __device__ __forceinline__ void gl_lds16(const void* g, void* lds) {
    __builtin_amdgcn_global_load_lds(
        (const __attribute__((address_space(1))) unsigned int*)g,
        (__attribute__((address_space(3))) unsigned int*)lds, 16, 0, 0);
}

// ---------------------------------------------------------------------------
// Projection (HBM-BW bound, ~5us): q scaled into exp2 domain, K plain,
// V pre-transposed. grid = B * S/16 * HSPLIT, block = 192.
// ---------------------------------------------------------------------------
__global__ __launch_bounds__(192)
void proj_kernel(const float* __restrict__ query, const float* __restrict__ key,
                 const float* __restrict__ value,
                 const float* __restrict__ Wq, const float* __restrict__ bq,
                 const float* __restrict__ Wk, const float* __restrict__ bk,
                 const float* __restrict__ Wv, const float* __restrict__ bv,
                 __hip_bfloat16* __restrict__ qp, __hip_bfloat16* __restrict__ kp,
                 __hip_bfloat16* __restrict__ vtp)
{
    const int tid  = threadIdx.x;
    const int wave = tid >> 6;
    const int lane = tid & 63;
    const int lr   = lane & 15;
    const int lh   = lane >> 4;
    const int ntile = S_ / 16;
    const int hb    = blockIdx.x % HSPLIT;
    const int sbase = ((blockIdx.x / HSPLIT) % ntile) * 16;
    const int b     = blockIdx.x / (ntile * HSPLIT);

    const float* x    = (wave == 0) ? query : (wave == 1) ? key : value;
    const float* W    = (wave == 0) ? Wq    : (wave == 1) ? Wk  : Wv;
    const float* bias = (wave == 0) ? bq    : (wave == 1) ? bk  : bv;

    bf16x8v wf[4][2];
#pragma unroll
    for (int cb = 0; cb < 4; ++cb)
#pragma unroll
        for (int hf = 0; hf < 2; ++hf)
#pragma unroll
            for (int j = 0; j < 8; ++j) {
                int e = lh * 8 + j + 32 * hf;
                wf[cb][hf][j] = (short)f2bf(W[e * E_ + cb * 16 + lr]);
            }

    float4 bias4[4];
    float  bvals[4];
#pragma unroll
    for (int cb = 0; cb < 4; ++cb) {
        bias4[cb] = *reinterpret_cast<const float4*>(bias + cb * 16 + 4 * lh);
        bvals[cb] = bias[cb * 16 + lr];
    }

    const float QSCALE = 0.18033688011112042f;   // log2e / 8

#pragma unroll
    for (int hi = 0; hi < H_ / HSPLIT; ++hi) {
        const int h = hb * (H_ / HSPLIT) + hi;
        const float* xrow = x + (((size_t)b * S_ + sbase + lr) * H_ + h) * E_;
        const float4* xr = reinterpret_cast<const float4*>(xrow);
        float4 a0 = xr[lh * 2], a1 = xr[lh * 2 + 1];
        float4 a2 = xr[8 + lh * 2], a3 = xr[8 + lh * 2 + 1];
        bf16x8v af[2];
        af[0][0] = (short)f2bf(a0.x); af[0][1] = (short)f2bf(a0.y);
        af[0][2] = (short)f2bf(a0.z); af[0][3] = (short)f2bf(a0.w);
        af[0][4] = (short)f2bf(a1.x); af[0][5] = (short)f2bf(a1.y);
        af[0][6] = (short)f2bf(a1.z); af[0][7] = (short)f2bf(a1.w);
        af[1][0] = (short)f2bf(a2.x); af[1][1] = (short)f2bf(a2.y);
        af[1][2] = (short)f2bf(a2.z); af[1][3] = (short)f2bf(a2.w);
        af[1][4] = (short)f2bf(a3.x); af[1][5] = (short)f2bf(a3.y);
        af[1][6] = (short)f2bf(a3.z); af[1][7] = (short)f2bf(a3.w);

        if (wave < 2) {
            __hip_bfloat16* dst = (wave == 0) ? qp : kp;
            const float scl = (wave == 0) ? QSCALE : 1.0f;
#pragma unroll
            for (int cb = 0; cb < 4; ++cb) {
                f32x4v acc = {0.f, 0.f, 0.f, 0.f};
                acc = __builtin_amdgcn_mfma_f32_16x16x32_bf16(wf[cb][0], af[0], acc, 0, 0, 0);
                acc = __builtin_amdgcn_mfma_f32_16x16x32_bf16(wf[cb][1], af[1], acc, 0, 0, 0);
                ushort4 o;
                o.x = f2bf((acc[0] + bias4[cb].x) * scl);
                o.y = f2bf((acc[1] + bias4[cb].y) * scl);
                o.z = f2bf((acc[2] + bias4[cb].z) * scl);
                o.w = f2bf((acc[3] + bias4[cb].w) * scl);
                *reinterpret_cast<ushort4*>(
                    (unsigned short*)dst +
                    (((size_t)b * H_ + h) * S_ + sbase + lr) * E_ + cb * 16 + 4 * lh) = o;
            }
        } else {
#pragma unroll
            for (int cb = 0; cb < 4; ++cb) {
                f32x4v acc = {0.f, 0.f, 0.f, 0.f};
                acc = __builtin_amdgcn_mfma_f32_16x16x32_bf16(af[0], wf[cb][0], acc, 0, 0, 0);
                acc = __builtin_amdgcn_mfma_f32_16x16x32_bf16(af[1], wf[cb][1], acc, 0, 0, 0);
                float bv4 = bvals[cb];
                ushort4 o;
                o.x = f2bf(acc[0] + bv4);
                o.y = f2bf(acc[1] + bv4);
                o.z = f2bf(acc[2] + bv4);
                o.w = f2bf(acc[3] + bv4);
                *reinterpret_cast<ushort4*>(
                    (unsigned short*)vtp +
                    (((size_t)b * H_ + h) * E_ + cb * 16 + lr) * S_ + sbase + 4 * lh) = o;
            }
        }
    }
}

// ---------------------------------------------------------------------------
// Flash attention (sound family, 5/5 validations incl. graph replays):
//   - global_load_lds double-buffered K/V staging
//   - __syncthreads() tile boundary (compiler-managed full drain — SOUND;
//     counted-vmcnt variants were intermittently racy: IR passes can hoist
//     the mask loads above the staging DMAs, breaking the vmcnt(4) count)
//   - mask loaded COALESCED one tile ahead, bit-packed in-register to a
//     64-bit row word via 2x shfl_xor
//   - raw exp2 softmax (|sc| <~ 8 << 127 overflow), deferred denominator
//   - XCD-bijective block swizzle (K/V L2 locality)
// grid = B*H * S/(QB*NW) = 1024, block = 256
// ---------------------------------------------------------------------------
__global__ __launch_bounds__(256, 4)
void attn_kernel(const __hip_bfloat16* __restrict__ qp,
                 const __hip_bfloat16* __restrict__ kp,
                 const __hip_bfloat16* __restrict__ vtp,
                 const int* __restrict__ mask,
                 float* __restrict__ out)
{
    __shared__ unsigned short Kt[2][KT * E_];    // swizzled [k][e], dbuf
    __shared__ unsigned short Vs[2][KT * E_];    // swizzled [e][k], dbuf
    __shared__ unsigned short Pt[NW][16 * KT];   // swizzled [q][k], per wave

    const int tid  = threadIdx.x;
    const int wave = tid >> 6;
    const int lane = tid & 63;
    const int lr   = lane & 15;
    const int lh   = lane >> 4;

    // XCD-bijective swizzle: grid 1024 = 8 chunks of 128 -> each XCD owns
    // 4 consecutive heads; their K/V (2 MB) stay L2-resident on that XCD.
    const int bid = blockIdx.x;
    const int swz = (bid & 7) * 128 + (bid >> 3);
    const int bh  = swz >> 5;
    const int qt  = swz & 31;
    const int qbase = qt * (QB * NW) + wave * QB;

    const __hip_bfloat16* qrow = qp + ((size_t)bh * S_ + qbase + lr) * E_;
    bf16x8v aq0 = *reinterpret_cast<const bf16x8v*>(qrow + lh * 8);
    bf16x8v aq1 = *reinterpret_cast<const bf16x8v*>(qrow + lh * 8 + 32);

    float psum[4];
    f32x4v Oa[4];
#pragma unroll
    for (int r = 0; r < 4; ++r) psum[r] = 0.f;
#pragma unroll
    for (int eb = 0; eb < 4; ++eb) Oa[eb] = {0.f, 0.f, 0.f, 0.f};

    const char* kgb = (const char*)(kp  + (size_t)bh * S_ * E_);
    const char* vgb = (const char*)(vtp + (size_t)bh * E_ * S_);
    // coalesced mask base: lane covers row lr, 16B chunk lh (of 4 per 64B seg)
    const char* mwb = (const char*)mask +
        (((size_t)bh * S_ + qbase + lr) * S_) * 4 + lh * 16;

    // K/V staging geometry: wave w stages rows [w*16, w*16+16); linear LDS
    // dest, source column pre-XOR'd to match the read-side swizzle
    const int rowA = wave * 16 + (lane >> 3);
    const int rowB = rowA + 8;
    const int e2   = (((lane & 7) ^ (lane >> 3)) << 4);
    const size_t koffA = (size_t)rowA * 128 + e2;        // + kb*128
    const size_t koffB = (size_t)rowB * 128 + e2;
    const size_t voffA = (size_t)rowA * (S_ * 2) + e2;   // + kb*2
    const size_t voffB = (size_t)rowB * (S_ * 2) + e2;

    char* Kt0 = (char*)(Kt[0]); char* Kt1 = (char*)(Kt[1]);
    char* Vs0 = (char*)(Vs[0]); char* Vs1 = (char*)(Vs[1]);
    char* PtB = (char*)(Pt[wave]);

    int4 mr0, mr1, mr2, mr3;   // coalesced raw mask regs (tile t)

    // ---- prologue: stage tile 0 into buf0; load mask tile 0 (coalesced)
    gl_lds16(kgb + koffA, Kt0 + wave * 2048);
    gl_lds16(kgb + koffB, Kt0 + wave * 2048 + 1024);
    gl_lds16(vgb + voffA, Vs0 + wave * 2048);
    gl_lds16(vgb + voffB, Vs0 + wave * 2048 + 1024);
    mr0 = *reinterpret_cast<const int4*>(mwb);
    mr1 = *reinterpret_cast<const int4*>(mwb + 64);
    mr2 = *reinterpret_cast<const int4*>(mwb + 128);
    mr3 = *reinterpret_cast<const int4*>(mwb + 192);
    __syncthreads();

    for (int kt = 0; kt < NT; ++kt) {
        const int kb  = kt * KT;
        char* KtC = (kt & 1) ? Kt1 : Kt0;
        char* VsC = (kt & 1) ? Vs1 : Vs0;
        char* KtN = (kt & 1) ? Kt0 : Kt1;
        char* VsN = (kt & 1) ? Vs0 : Vs1;
        const bool pref = (kt + 1 < NT);

        // ---- issue next tile's K/V staging (async DMA, cannot be sunk)
        if (pref) {
            const size_t kadd = (size_t)(kb + KT) * 128;
            const size_t vadd = (size_t)(kb + KT) * 2;
            gl_lds16(kgb + kadd + koffA, KtN + wave * 2048);
            gl_lds16(kgb + kadd + koffB, KtN + wave * 2048 + 1024);
            gl_lds16(vgb + vadd + voffA, VsN + wave * 2048);
            gl_lds16(vgb + vadd + voffB, VsN + wave * 2048 + 1024);
        }

        // ---- pack THIS tile's mask (regs loaded last iter, long resolved):
        // bit p of wm = mask int p of row lr;   p = lh*4 + i*16 + j
        unsigned long long wm;
        {
            unsigned n0 = (mr0.x & 1) | ((mr0.y & 1) << 1) | ((mr0.z & 1) << 2) | ((mr0.w & 1) << 3);
            unsigned n1 = (mr1.x & 1) | ((mr1.y & 1) << 1) | ((mr1.z & 1) << 2) | ((mr1.w & 1) << 3);
            unsigned n2 = (mr2.x & 1) | ((mr2.y & 1) << 1) | ((mr2.z & 1) << 2) | ((mr2.w & 1) << 3);
            unsigned n3 = (mr3.x & 1) | ((mr3.y & 1) << 1) | ((mr3.z & 1) << 2) | ((mr3.w & 1) << 3);
            int sh = lh * 4;
            wm = ((unsigned long long)n0 << sh) |
                 ((unsigned long long)n1 << (sh + 16)) |
                 ((unsigned long long)n2 << (sh + 32)) |
                 ((unsigned long long)n3 << (sh + 48));
            wm |= __shfl_xor(wm, 16);
            wm |= __shfl_xor(wm, 32);   // all 4 lanes of row lr now hold word
        }

        // ---- issue next tile's coalesced mask loads
        if (pref) {
            const char* mp = mwb + (size_t)(kb + KT) * 4;
            mr0 = *reinterpret_cast<const int4*>(mp);
            mr1 = *reinterpret_cast<const int4*>(mp + 64);
            mr2 = *reinterpret_cast<const int4*>(mp + 128);
            mr3 = *reinterpret_cast<const int4*>(mp + 192);
        }

        // ---- QK^T : D layout row = 4*lh+r (q), col = lr (k within cb)
        f32x4v sc[4];
#pragma unroll
        for (int cb = 0; cb < 4; ++cb) {
            int kcol = cb * 16 + lr;
            bf16x8v bk0 = *reinterpret_cast<bf16x8v*>(
                KtC + ((kcol * 128 + lh * 16) ^ ((kcol & 7) << 4)));
            bf16x8v bk1 = *reinterpret_cast<bf16x8v*>(
                KtC + ((kcol * 128 + 64 + lh * 16) ^ ((kcol & 7) << 4)));
            f32x4v a = {0.f, 0.f, 0.f, 0.f};
            a = __builtin_amdgcn_mfma_f32_16x16x32_bf16(aq0, bk0, a, 0, 0, 0);
            a = __builtin_amdgcn_mfma_f32_16x16x32_bf16(aq1, bk1, a, 0, 0, 0);
            sc[cb] = a;
        }

        // ---- P = exp2(sc) raw (|sc| <~ 8 << 127 overflow); per-lane partial
        // denominators; write P (bf16) to per-wave swizzled LDS tile.
#pragma unroll
        for (int r = 0; r < 4; ++r) {
            int q = 4 * lh + r;
            float rs = 0.f;
#pragma unroll
            for (int cb = 0; cb < 4; ++cb) {
                float pv = __builtin_amdgcn_exp2f(sc[cb][r]);
                rs += pv;
                *reinterpret_cast<unsigned short*>(
                    PtB + ((q * 128 + (cb * 16 + lr) * 2) ^ ((q & 7) << 4))) = f2bf(pv);
            }
            psum[r] += rs;
        }

        // ---- PV, dropout via bit-test on the row word (k = mh*32 + lh*8 + j)
#pragma unroll
        for (int mh = 0; mh < 2; ++mh) {
            int k0 = mh * 32 + lh * 8;
            bf16x8v pa = *reinterpret_cast<bf16x8v*>(
                PtB + ((lr * 128 + k0 * 2) ^ ((lr & 7) << 4)));
            unsigned mby = (unsigned)(wm >> ((mh * 4 + lh) * 8)) & 0xffu;
#pragma unroll
            for (int j = 0; j < 8; ++j)
                pa[j] = (mby & (1u << j)) ? pa[j] : (short)0;
#pragma unroll
            for (int eb = 0; eb < 4; ++eb) {
                int e = eb * 16 + lr;
                bf16x8v vb = *reinterpret_cast<bf16x8v*>(
                    VsC + ((e * 128 + k0 * 2) ^ ((e & 7) << 4)));
                Oa[eb] = __builtin_amdgcn_mfma_f32_16x16x32_bf16(pa, vb, Oa[eb], 0, 0, 0);
            }
        }

        __syncthreads();   // drains: next tile's staging landed, bufs safe
    }

    // ---- epilogue: reduce denominators once; out = O * (1/0.9) / lsum
    constexpr float KEEP_INV = 1.0f / 0.9f;
    float* orow = out + ((size_t)bh * S_ + qbase) * E_;
#pragma unroll
    for (int r = 0; r < 4; ++r) {
        float s = psum[r];
#pragma unroll
        for (int off = 1; off < 16; off <<= 1)
            s += __shfl_xor(s, off);
        float inv = KEEP_INV / s;
        int q = 4 * lh + r;
#pragma unroll
        for (int eb = 0; eb < 4; ++eb)
            orow[(size_t)q * E_ + eb * 16 + lr] = Oa[eb][r] * inv;
    }
}

extern "C" void kernel_launch(void* const* d_in, const int* in_sizes, int n_in,
                              void* d_out, int out_size, void* d_ws, size_t ws_size,
                              hipStream_t stream) {
    (void)in_sizes; (void)n_in; (void)out_size; (void)ws_size;
    const float* query = (const float*)d_in[0];
    const float* key   = (const float*)d_in[1];
    const float* value = (const float*)d_in[2];
    const float* Wq    = (const float*)d_in[3];
    const float* bq    = (const float*)d_in[4];
    const float* Wk    = (const float*)d_in[5];
    const float* bk    = (const float*)d_in[6];
    const float* Wv    = (const float*)d_in[7];
    const float* bv    = (const float*)d_in[8];
    const int*   mask  = (const int*)d_in[9];
    float*       out   = (float*)d_out;

    const size_t per = (size_t)B_ * H_ * S_ * E_;
    __hip_bfloat16* qp  = (__hip_bfloat16*)d_ws;
    __hip_bfloat16* kp  = qp + per;
    __hip_bfloat16* vtp = kp + per;

    proj_kernel<<<B_ * (S_ / 16) * HSPLIT, 192, 0, stream>>>(query, key, value,
                                                             Wq, bq, Wk, bk, Wv, bv,
                                                             qp, kp, vtp);
    attn_kernel<<<B_ * H_ * (S_ / (QB * NW)), 256, 0, stream>>>(qp, kp, vtp, mask, out);
}